// Round 4
// baseline (458.715 us; speedup 1.0000x reference)
//
#include <hip/hip_runtime.h>

#define B_TOT 4096
#define S_LEN 1024
#define HID 30
#define SKIP 16
#define HLEN (S_LEN - SKIP)   // 1008

typedef float f32x2 __attribute__((ext_vector_type(2)));

// ---- DPP helpers (16-lane rows) ----
template <int CTRL>
__device__ __forceinline__ float dppmov(float v) {
  return __int_as_float(__builtin_amdgcn_update_dpp(
      0, __float_as_int(v), CTRL, 0xF, 0xF, true));
}
template <int CTRL>
__device__ __forceinline__ float dpp_add(float v) { return v + dppmov<CTRL>(v); }

__device__ __forceinline__ float swz_xor16(float v) {
  return __int_as_float(__builtin_amdgcn_ds_swizzle(__float_as_int(v), 0x401F));
}

// sum over each 32-lane group; result valid in ALL 32 lanes
__device__ __forceinline__ float red32(float v) {
  v = dpp_add<0xB1>(v);    // xor1
  v = dpp_add<0x4E>(v);    // xor2
  v = dpp_add<0x141>(v);   // xor7 (row_half_mirror)
  v = dpp_add<0x140>(v);   // xor15 (row_mirror)
  v += swz_xor16(v);       // xor16 across the 16-row boundary
  return v;
}

// full 32-lane butterfly (MLP kernel)
__device__ __forceinline__ float swz_add_all(float v) {
  v += __int_as_float(__builtin_amdgcn_ds_swizzle(__float_as_int(v), 0x041F));
  v += __int_as_float(__builtin_amdgcn_ds_swizzle(__float_as_int(v), 0x081F));
  v += __int_as_float(__builtin_amdgcn_ds_swizzle(__float_as_int(v), 0x101F));
  v += __int_as_float(__builtin_amdgcn_ds_swizzle(__float_as_int(v), 0x201F));
  v += swz_xor16(v);
  return v;
}

// hp[m] = (h of lane l^m, h of lane l^16^m), m=0..15  (within 32-group)
// hx must already hold h of lane l^16.
__device__ __forceinline__ void gather_pairs(float h, float hx, f32x2* hp) {
  hp[0]  = f32x2{h, hx};
  hp[1]  = f32x2{dppmov<0xB1>(h),  dppmov<0xB1>(hx)};   // xor1
  hp[2]  = f32x2{dppmov<0x4E>(h),  dppmov<0x4E>(hx)};   // xor2
  hp[3]  = f32x2{dppmov<0x1B>(h),  dppmov<0x1B>(hx)};   // xor3
  hp[7]  = f32x2{dppmov<0x141>(h), dppmov<0x141>(hx)};  // xor7
  hp[15] = f32x2{dppmov<0x140>(h), dppmov<0x140>(hx)};  // xor15
  hp[4]  = f32x2{dppmov<0x1B>(hp[7].x),  dppmov<0x1B>(hp[7].y)};   // 7^3
  hp[5]  = f32x2{dppmov<0x4E>(hp[7].x),  dppmov<0x4E>(hp[7].y)};   // 7^2
  hp[6]  = f32x2{dppmov<0xB1>(hp[7].x),  dppmov<0xB1>(hp[7].y)};   // 7^1
  hp[8]  = f32x2{dppmov<0x141>(hp[15].x),dppmov<0x141>(hp[15].y)}; // 15^7
  hp[12] = f32x2{dppmov<0x1B>(hp[15].x), dppmov<0x1B>(hp[15].y)};  // 15^3
  hp[13] = f32x2{dppmov<0x4E>(hp[15].x), dppmov<0x4E>(hp[15].y)};  // 15^2
  hp[14] = f32x2{dppmov<0xB1>(hp[15].x), dppmov<0xB1>(hp[15].y)};  // 15^1
  hp[9]  = f32x2{dppmov<0xB1>(hp[8].x),  dppmov<0xB1>(hp[8].y)};   // 8^1
  hp[10] = f32x2{dppmov<0x4E>(hp[8].x),  dppmov<0x4E>(hp[8].y)};   // 8^2
  hp[11] = f32x2{dppmov<0x1B>(hp[8].x),  dppmov<0x1B>(hp[8].y)};   // 8^3
}

__device__ __forceinline__ float sigmoid_fast(float z) {
  float e = __builtin_amdgcn_exp2f(z * -1.442695041f);   // exp(-z)
  return __builtin_amdgcn_rcpf(1.0f + e);                // 1/(1+e)
}

// 32 lanes per batch; lane owns row j = lane-in-group (rows 30,31 dummy).
__global__ __launch_bounds__(256) void mminet_main(
    const float* __restrict__ x,   const float* __restrict__ var,
    const float* __restrict__ amps,const float* __restrict__ s0,
    const float* __restrict__ W1,  const float* __restrict__ b1,
    const float* __restrict__ Wx,  const float* __restrict__ Wh,
    const float* __restrict__ W2,  const float* __restrict__ b2,
    float* __restrict__ Hout, float* __restrict__ Pws)
{
  const int tid = threadIdx.x;
  const int l   = tid & 31;                    // lane within 32-group = row j
  const int b   = blockIdx.x * 8 + (tid >> 5);
  const bool act = (l < HID);

  const float v0 = var[b*4+0], v1 = var[b*4+1], v2 = var[b*4+2], v3 = var[b*4+3];

  // ---- per-lane row constants ----
  float wx0=0,wx1=0,wx2=0,cvar=0,w1i=0,w2i=0;
  if (act) {
    wx0 = Wx[l*7+0]; wx1 = Wx[l*7+1]; wx2 = Wx[l*7+2];
    cvar = Wx[l*7+3]*v0 + Wx[l*7+4]*v1 + Wx[l*7+5]*v2 + Wx[l*7+6]*v3;
    w1i = W1[l]; w2i = W2[l];
  }

  // ---- Wh row in xor-pair order: wp[m] = (Wh[l][l^m], Wh[l][l^16^m]) ----
  f32x2 wp[16];
  float rowsum = 0.f;
#pragma unroll
  for (int m = 0; m < 16; ++m) {
    const int cO = l ^ m, cT = l ^ 16 ^ m;
    float a = (act && cO < HID) ? Wh[l*HID + cO] : 0.f;
    float c = (act && cT < HID) ? Wh[l*HID + cT] : 0.f;
    wp[m] = f32x2{a, c};
    rowsum += a + c;
  }

  const float hcst = W1[30]*v0 + W1[31]*v1 + W1[32]*v2 + W1[33]*v3 + b1[0];
  const float hc2  = hcst + b2[0];
  const float sumW2 = red32(w2i);
  const float r = 5.0f * (float)(l + 1) / 30.0f;

  const float4* xb = (const float4*)(x + (size_t)b * S_LEN * 4);

  // ---- state ----
  float s1 = act ? s0[b*HID + l] : 0.f;
  float h, hx;

  // ---- t = 0 prologue ----
  {
    float4 xv = xb[0];
    s1 = fminf(fmaxf(xv.y + s1, -r), r);
    float Hh0 = red32(w1i * s1) + hcst;
    float hpre = (xv.x - Hh0) / sumW2;          // uniform initial h2
    float z = cvar + wx0*xv.x + wx1*xv.z + wx2*xv.w + rowsum*hpre;
    h = sigmoid_fast(z);
    hx = swz_xor16(h);
  }

  // one RNN step; returns per-lane partial w1*s1 + w2*h
  auto step = [&](const float4 xq) -> float {
    s1 = fminf(fmaxf(xq.y + s1, -r), r);
    f32x2 hp[16];
    gather_pairs(h, hx, hp);
    f32x2 acc = f32x2{fmaf(wx0, xq.x, cvar), fmaf(wx1, xq.z, wx2 * xq.w)};
#pragma unroll
    for (int m = 0; m < 16; ++m)
      acc = __builtin_elementwise_fma(wp[m], hp[m], acc);  // v_pk_fma_f32
    h = sigmoid_fast(acc.x + acc.y);
    hx = swz_xor16(h);                       // overlap swizzle with next step
    return fmaf(w1i, s1, w2i * h);
  };

  // ---- t = 1..15 : outputs discarded, recurrence only ----
  for (int t = 1; t < SKIP; ++t) (void)step(xb[t]);

  // ---- t = 16..1023 in blocks of 4 ----
  float P = 0.f, Hprev = 0.f, Bprev = 0.f;
  const float am0 = amps[b*2+0], am1 = amps[b*2+1];

  float4 xc0 = xb[SKIP+0], xc1 = xb[SKIP+1], xc2 = xb[SKIP+2], xc3 = xb[SKIP+3];

  for (int t = SKIP; t < S_LEN; t += 4) {
    const int tn = (t + 4 < S_LEN) ? (t + 4) : t;   // uniform
    float4 xn0 = xb[tn+0], xn1 = xb[tn+1], xn2 = xb[tn+2], xn3 = xb[tn+3];

    float p[4], x0s[4];
    x0s[0] = xc0.x;  p[0] = step(xc0);
    x0s[1] = xc1.x;  p[1] = step(xc1);
    x0s[2] = xc2.x;  p[2] = step(xc2);
    x0s[3] = xc3.x;  p[3] = step(xc3);

#pragma unroll
    for (int u = 0; u < 4; ++u) p[u] = red32(p[u]);

    float hq[4];
#pragma unroll
    for (int u = 0; u < 4; ++u) {
      float Ht = p[u] + hc2;
      hq[u] = Ht;
      if (t + u > SKIP) P += (x0s[u] - Bprev) * (Ht + Hprev);
      Hprev = Ht; Bprev = x0s[u];
    }
    if (l == 0) {
      *(float4*)(Hout + (size_t)b * HLEN + (t - SKIP)) =
          make_float4(hq[0], hq[1], hq[2], hq[3]);
    }
    xc0 = xn0; xc1 = xn1; xc2 = xn2; xc3 = xn3;
  }
  if (l == 0) Pws[b] = P * 0.5f * am0 * am1;
}

// one wave per batch: lane n computes h1_n; LDS round-trip; 32-group dot+reduce
__global__ __launch_bounds__(256) void mminet_mlp(
    const float* __restrict__ var, const float* __restrict__ Pws,
    const float* __restrict__ Wm1, const float* __restrict__ bm1,
    const float* __restrict__ Wm2, const float* __restrict__ bm2,
    const float* __restrict__ Wm3, const float* __restrict__ bm3,
    float* __restrict__ out2)
{
  __shared__ float h1s[4][64];
  const int tid  = threadIdx.x;
  const int w    = tid >> 6;
  const int lane = tid & 63;
  const int b    = blockIdx.x * 4 + w;

  const float v0 = var[b*4+0], v1 = var[b*4+1], v2 = var[b*4+2], v3 = var[b*4+3];
  float P = Pws[b] * __builtin_amdgcn_exp2f(v0 * 3.321928095f);  // * 10^var0
  P = fmaxf(P, 1e-12f);
  const float Pcv = __builtin_amdgcn_logf(P) * 0.30102999566f;   // log10

  const float* wr = Wm1 + lane * 5;
  float h1 = bm1[lane] + wr[0]*v0 + wr[1]*v1 + wr[2]*v2 + wr[3]*v3 + wr[4]*Pcv;
  h1s[w][lane] = fmaxf(h1, 0.f);   // wave-synchronous LDS round trip

  const int m = lane & 31;
  const float4* w2r = (const float4*)(Wm2 + m * 64);
  const float4* h1v = (const float4*)&h1s[w][0];
  float z = bm2[m];
#pragma unroll
  for (int q = 0; q < 16; ++q) {
    float4 ww = w2r[q], hh = h1v[q];
    z += ww.x*hh.x + ww.y*hh.y + ww.z*hh.z + ww.w*hh.w;
  }
  float t = Wm3[m] * fmaxf(z, 0.f);
  t = swz_add_all(t);
  if (lane == 0) out2[b] = Pcv + t + bm3[0];
}

extern "C" void kernel_launch(void* const* d_in, const int* in_sizes, int n_in,
                              void* d_out, int out_size, void* d_ws, size_t ws_size,
                              hipStream_t stream)
{
  const float* x    = (const float*)d_in[0];
  const float* var  = (const float*)d_in[1];
  const float* amps = (const float*)d_in[2];
  const float* s0   = (const float*)d_in[3];
  const float* W1   = (const float*)d_in[4];
  const float* b1   = (const float*)d_in[5];
  const float* Wx   = (const float*)d_in[6];
  const float* Wh   = (const float*)d_in[7];
  const float* W2   = (const float*)d_in[8];
  const float* b2   = (const float*)d_in[9];
  const float* Wm1  = (const float*)d_in[10];
  const float* bm1  = (const float*)d_in[11];
  const float* Wm2  = (const float*)d_in[12];
  const float* bm2  = (const float*)d_in[13];
  const float* Wm3  = (const float*)d_in[14];
  const float* bm3  = (const float*)d_in[15];
  // d_in[16] = n_init (compile-time 16)

  float* Hout = (float*)d_out;
  float* out2 = (float*)d_out + (size_t)B_TOT * HLEN;
  float* Pws  = (float*)d_ws;

  mminet_main<<<B_TOT / 8, 256, 0, stream>>>(x, var, amps, s0, W1, b1, Wx, Wh,
                                             W2, b2, Hout, Pws);
  mminet_mlp<<<B_TOT / 4, 256, 0, stream>>>(var, Pws, Wm1, bm1, Wm2, bm2,
                                            Wm3, bm3, out2);
}

// Round 5
// 378.123 us; speedup vs baseline: 1.2131x; 1.2131x over previous
//
#include <hip/hip_runtime.h>

#define B_TOT 4096
#define S_LEN 1024
#define HID 30
#define SKIP 16
#define HLEN (S_LEN - SKIP)   // 1008

// ---- DPP helpers (16-lane groups == DPP rows) ----
template <int CTRL>
__device__ __forceinline__ float dppmov(float v) {
  return __int_as_float(__builtin_amdgcn_update_dpp(
      0, __float_as_int(v), CTRL, 0xF, 0xF, true));
}
template <int CTRL>
__device__ __forceinline__ float dpp_add(float v) { return v + dppmov<CTRL>(v); }

// sum over each 16-lane group; result valid in ALL 16 lanes
__device__ __forceinline__ float red16(float v) {
  v = dpp_add<0xB1>(v);    // quad_perm [1,0,3,2] : xor1
  v = dpp_add<0x4E>(v);    // quad_perm [2,3,0,1] : xor2
  v = dpp_add<0x141>(v);   // row_half_mirror     : xor7
  v = dpp_add<0x140>(v);   // row_mirror          : xor15
  return v;
}

// all-gather: a[m] = value of lane (lane ^ m) within the 16-group
__device__ __forceinline__ void gather16(float h, float* a) {
  a[0]  = h;
  a[1]  = dppmov<0xB1>(h);      // xor1
  a[2]  = dppmov<0x4E>(h);      // xor2
  a[3]  = dppmov<0x1B>(h);      // xor3
  a[7]  = dppmov<0x141>(h);     // xor7
  a[15] = dppmov<0x140>(h);     // xor15
  a[4]  = dppmov<0x1B>(a[7]);   // 7^3
  a[5]  = dppmov<0x4E>(a[7]);   // 7^2
  a[6]  = dppmov<0xB1>(a[7]);   // 7^1
  a[8]  = dppmov<0x141>(a[15]); // 15^7
  a[12] = dppmov<0x1B>(a[15]);  // 15^3
  a[13] = dppmov<0x4E>(a[15]);  // 15^2
  a[14] = dppmov<0xB1>(a[15]);  // 15^1
  a[9]  = dppmov<0xB1>(a[8]);   // 8^1
  a[10] = dppmov<0x4E>(a[8]);   // 8^2
  a[11] = dppmov<0x1B>(a[8]);   // 8^3
}

__device__ __forceinline__ float sigmoid_fast(float z) {
  float e = __builtin_amdgcn_exp2f(z * -1.442695041f);   // exp(-z)
  return __builtin_amdgcn_rcpf(1.0f + e);                // 1/(1+e)
}

// 16 lanes per batch; lane owns rows j0=2l, j1=2l+1 (rows 30,31 dummy).
// Fused: RNN scan + trapezoid integral + final 5->64->32->1 MLP.
__global__ __launch_bounds__(256) void mminet_fused(
    const float* __restrict__ x,   const float* __restrict__ var,
    const float* __restrict__ amps,const float* __restrict__ s0,
    const float* __restrict__ W1,  const float* __restrict__ b1,
    const float* __restrict__ Wx,  const float* __restrict__ Wh,
    const float* __restrict__ W2,  const float* __restrict__ b2,
    const float* __restrict__ Wm1, const float* __restrict__ bm1,
    const float* __restrict__ Wm2, const float* __restrict__ bm2,
    const float* __restrict__ Wm3, const float* __restrict__ bm3,
    float* __restrict__ Hout, float* __restrict__ out2)
{
  __shared__ float mlpbuf[16][64];           // 4 KB, epilogue only
  const int tid  = threadIdx.x;
  const int l    = tid & 15;                 // lane within 16-group
  const int grp  = tid >> 4;                 // group within block (0..15)
  const int b    = blockIdx.x * 16 + grp;
  const int j0   = 2 * l, j1 = 2 * l + 1;
  const bool a0r = (j0 < HID), a1r = (j1 < HID);

  const float v0 = var[b*4+0], v1 = var[b*4+1], v2 = var[b*4+2], v3 = var[b*4+3];

  // ---- per-lane row constants ----
  float wx0A=0,wx1A=0,wx2A=0,cvA=0,w1A=0,w2A=0;
  float wx0B=0,wx1B=0,wx2B=0,cvB=0,w1B=0,w2B=0;
  if (a0r) {
    wx0A=Wx[j0*7+0]; wx1A=Wx[j0*7+1]; wx2A=Wx[j0*7+2];
    cvA = Wx[j0*7+3]*v0 + Wx[j0*7+4]*v1 + Wx[j0*7+5]*v2 + Wx[j0*7+6]*v3;
    w1A = W1[j0]; w2A = W2[j0];
  }
  if (a1r) {
    wx0B=Wx[j1*7+0]; wx1B=Wx[j1*7+1]; wx2B=Wx[j1*7+2];
    cvB = Wx[j1*7+3]*v0 + Wx[j1*7+4]*v1 + Wx[j1*7+5]*v2 + Wx[j1*7+6]*v3;
    w1B = W1[j1]; w2B = W2[j1];
  }

  // ---- Wh in xor-relative order: partner pair m comes from lane l^m ----
  float wA0[16], wA1[16], wB0[16], wB1[16];
  float rowsumA = 0.f, rowsumB = 0.f;
#pragma unroll
  for (int m = 0; m < 16; ++m) {
    const int lp = l ^ m;
    const int c0 = 2 * lp, c1 = 2 * lp + 1;
    float a0 = (a0r && c0 < HID) ? Wh[j0*HID + c0] : 0.f;
    float a1 = (a0r && c1 < HID) ? Wh[j0*HID + c1] : 0.f;
    float b0 = (a1r && c0 < HID) ? Wh[j1*HID + c0] : 0.f;
    float b1w= (a1r && c1 < HID) ? Wh[j1*HID + c1] : 0.f;
    wA0[m] = a0; wA1[m] = a1; wB0[m] = b0; wB1[m] = b1w;
    rowsumA += a0 + a1; rowsumB += b0 + b1w;
  }

  const float hcst = W1[30]*v0 + W1[31]*v1 + W1[32]*v2 + W1[33]*v3 + b1[0];
  const float hc2  = hcst + b2[0];
  const float sumW2 = red16(w2A + w2B);

  const float rA = 5.0f * (float)(j0 + 1) / 30.0f;
  const float rB = 5.0f * (float)(j1 + 1) / 30.0f;

  const float4* xb = (const float4*)(x + (size_t)b * S_LEN * 4);

  // ---- state ----
  float s1A = a0r ? s0[b*HID + j0] : 0.f;
  float s1B = a1r ? s0[b*HID + j1] : 0.f;
  float hA, hB;

  // ---- t = 0 prologue ----
  {
    float4 xv = xb[0];
    s1A = fminf(fmaxf(xv.y + s1A, -rA), rA);
    s1B = fminf(fmaxf(xv.y + s1B, -rB), rB);
    float Hh0 = red16(fmaf(w1A, s1A, w1B * s1B)) + hcst;
    float hpre = (xv.x - Hh0) / sumW2;         // uniform initial h2
    float zA = cvA + wx0A*xv.x + wx1A*xv.z + wx2A*xv.w + rowsumA*hpre;
    float zB = cvB + wx0B*xv.x + wx1B*xv.z + wx2B*xv.w + rowsumB*hpre;
    hA = sigmoid_fast(zA);
    hB = sigmoid_fast(zB);
  }

  // one RNN step: 8 independent FMA chains of 8 (shorter dep chain)
  auto step = [&](const float4 xq) -> float {
    s1A = fminf(fmaxf(xq.y + s1A, -rA), rA);
    s1B = fminf(fmaxf(xq.y + s1B, -rB), rB);
    float he[16], ho[16];
    gather16(hA, he);
    gather16(hB, ho);
    float zA0 = fmaf(wx0A, xq.x, cvA);
    float zA1 = fmaf(wx1A, xq.z, wx2A * xq.w);
    float zB0 = fmaf(wx0B, xq.x, cvB);
    float zB1 = fmaf(wx1B, xq.z, wx2B * xq.w);
    float zA2 = 0.f, zA3 = 0.f, zB2 = 0.f, zB3 = 0.f;
#pragma unroll
    for (int m = 0; m < 8; ++m) {
      zA0 = fmaf(wA0[m],   he[m],   zA0);
      zA1 = fmaf(wA1[m],   ho[m],   zA1);
      zB0 = fmaf(wB0[m],   he[m],   zB0);
      zB1 = fmaf(wB1[m],   ho[m],   zB1);
      zA2 = fmaf(wA0[m+8], he[m+8], zA2);
      zA3 = fmaf(wA1[m+8], ho[m+8], zA3);
      zB2 = fmaf(wB0[m+8], he[m+8], zB2);
      zB3 = fmaf(wB1[m+8], ho[m+8], zB3);
    }
    float zA = (zA0 + zA2) + (zA1 + zA3);
    float zB = (zB0 + zB2) + (zB1 + zB3);
    hA = sigmoid_fast(zA);
    hB = sigmoid_fast(zB);
    return fmaf(w1A, s1A, fmaf(w1B, s1B, fmaf(w2A, hA, w2B * hB)));
  };

  // ---- t = 1..15 : outputs discarded, recurrence only ----
  for (int t = 1; t < SKIP; ++t) (void)step(xb[t]);

  // ---- t = 16..1023 in blocks of 4 ----
  float P = 0.f, Hprev = 0.f, Bprev = 0.f;
  const float am0 = amps[b*2+0], am1 = amps[b*2+1];

  float4 xc0 = xb[SKIP+0], xc1 = xb[SKIP+1], xc2 = xb[SKIP+2], xc3 = xb[SKIP+3];

  for (int t = SKIP; t < S_LEN; t += 4) {
    const int tn = (t + 4 < S_LEN) ? (t + 4) : t;   // uniform
    float4 xn0 = xb[tn+0], xn1 = xb[tn+1], xn2 = xb[tn+2], xn3 = xb[tn+3];

    float p[4], x0s[4];
    x0s[0] = xc0.x;  p[0] = step(xc0);
    x0s[1] = xc1.x;  p[1] = step(xc1);
    x0s[2] = xc2.x;  p[2] = step(xc2);
    x0s[3] = xc3.x;  p[3] = step(xc3);

#pragma unroll
    for (int u = 0; u < 4; ++u) p[u] = red16(p[u]);

    float hq[4];
#pragma unroll
    for (int u = 0; u < 4; ++u) {
      float Ht = p[u] + hc2;
      hq[u] = Ht;
      if (t + u > SKIP) P += (x0s[u] - Bprev) * (Ht + Hprev);
      Hprev = Ht; Bprev = x0s[u];
    }
    if (l == 0) {
      *(float4*)(Hout + (size_t)b * HLEN + (t - SKIP)) =
          make_float4(hq[0], hq[1], hq[2], hq[3]);
    }
    xc0 = xn0; xc1 = xn1; xc2 = xn2; xc3 = xn3;
  }

  // ==== fused MLP epilogue (once per batch; P valid in all 16 lanes) ====
  float Pp = P * 0.5f * am0 * am1;
  Pp *= __builtin_amdgcn_exp2f(v0 * 3.321928095f);     // * 10^var0
  Pp = fmaxf(Pp, 1e-12f);
  const float Pcv = __builtin_amdgcn_logf(Pp) * 0.30102999566f;  // log10

  float* hs = &mlpbuf[grp][0];
#pragma unroll
  for (int q = 0; q < 4; ++q) {
    const int n = l + 16 * q;
    const float* wr = Wm1 + n * 5;
    float h1 = bm1[n] + wr[0]*v0 + wr[1]*v1 + wr[2]*v2 + wr[3]*v3 + wr[4]*Pcv;
    hs[n] = fmaxf(h1, 0.f);                  // wave-synchronous within group
  }
  const int m0 = l, m1 = l + 16;
  const float4* h1v = (const float4*)hs;
  const float4* w2a = (const float4*)(Wm2 + m0 * 64);
  const float4* w2b = (const float4*)(Wm2 + m1 * 64);
  float z0 = bm2[m0], z1 = bm2[m1];
#pragma unroll
  for (int q = 0; q < 16; ++q) {
    float4 hh = h1v[q];
    float4 wa = w2a[q], wb = w2b[q];
    z0 += wa.x*hh.x + wa.y*hh.y + wa.z*hh.z + wa.w*hh.w;
    z1 += wb.x*hh.x + wb.y*hh.y + wb.z*hh.z + wb.w*hh.w;
  }
  float sp = Wm3[m0] * fmaxf(z0, 0.f) + Wm3[m1] * fmaxf(z1, 0.f);
  sp = red16(sp);
  if (l == 0) out2[b] = Pcv + sp + bm3[0];
}

extern "C" void kernel_launch(void* const* d_in, const int* in_sizes, int n_in,
                              void* d_out, int out_size, void* d_ws, size_t ws_size,
                              hipStream_t stream)
{
  const float* x    = (const float*)d_in[0];
  const float* var  = (const float*)d_in[1];
  const float* amps = (const float*)d_in[2];
  const float* s0   = (const float*)d_in[3];
  const float* W1   = (const float*)d_in[4];
  const float* b1   = (const float*)d_in[5];
  const float* Wx   = (const float*)d_in[6];
  const float* Wh   = (const float*)d_in[7];
  const float* W2   = (const float*)d_in[8];
  const float* b2   = (const float*)d_in[9];
  const float* Wm1  = (const float*)d_in[10];
  const float* bm1  = (const float*)d_in[11];
  const float* Wm2  = (const float*)d_in[12];
  const float* bm2  = (const float*)d_in[13];
  const float* Wm3  = (const float*)d_in[14];
  const float* bm3  = (const float*)d_in[15];
  // d_in[16] = n_init (compile-time 16)

  float* Hout = (float*)d_out;
  float* out2 = (float*)d_out + (size_t)B_TOT * HLEN;

  mminet_fused<<<B_TOT / 16, 256, 0, stream>>>(
      x, var, amps, s0, W1, b1, Wx, Wh, W2, b2,
      Wm1, bm1, Wm2, bm2, Wm3, bm3, Hout, out2);
}